// Round 1
// baseline (407.580 us; speedup 1.0000x reference)
//
#include <hip/hip_runtime.h>
#include <math.h>

// One block per output row. 256 threads x 8 elems = 2048 = FC1/2.
// d_out layout (all float32): [N*d] quantized values, then [N] quant_scale.

#define THREADS 256

__global__ __launch_bounds__(THREADS) void swiglu_moe_quant_kernel(
    const float* __restrict__ input,          // [N, 2*d]
    const float* __restrict__ smooth_scale,   // [E, d]
    const int*   __restrict__ sorted_token_ids, // [N]
    const int*   __restrict__ topk_indices,     // [N]
    float* __restrict__ q_out,                // [N, d] quantized values (as f32)
    float* __restrict__ scale_out,            // [N]
    int d)                                     // = FC1/2 (2048)
{
    const int row  = blockIdx.x;
    const int tok  = sorted_token_ids[row];
    const int exp_ = topk_indices[row];

    const float* g  = input + (size_t)tok * (size_t)(2 * d);
    const float* up = g + d;
    const float* ss = smooth_scale + (size_t)exp_ * (size_t)d;

    const int t = threadIdx.x;
    const int iters = d / (THREADS * 4);   // 2 for d=2048

    float4 act[8];   // supports d up to 8*THREADS*4; harness uses iters=2
    float amax = 0.0f;

    #pragma unroll 2
    for (int k = 0; k < iters; ++k) {
        const int j = (t + k * THREADS) * 4;
        float4 gv = *(const float4*)(g  + j);
        float4 uv = *(const float4*)(up + j);
        float4 sv = *(const float4*)(ss + j);
        float4 a;
        a.x = (gv.x / (1.0f + expf(-gv.x))) * uv.x * sv.x;
        a.y = (gv.y / (1.0f + expf(-gv.y))) * uv.y * sv.y;
        a.z = (gv.z / (1.0f + expf(-gv.z))) * uv.z * sv.z;
        a.w = (gv.w / (1.0f + expf(-gv.w))) * uv.w * sv.w;
        act[k] = a;
        amax = fmaxf(amax, fmaxf(fmaxf(fabsf(a.x), fabsf(a.y)),
                                 fmaxf(fabsf(a.z), fabsf(a.w))));
    }

    // Wave (64-lane) max reduction, then cross-wave via LDS.
    #pragma unroll
    for (int off = 32; off > 0; off >>= 1)
        amax = fmaxf(amax, __shfl_down(amax, off));

    __shared__ float wave_max[THREADS / 64];
    const int wave = t >> 6;
    const int lane = t & 63;
    if (lane == 0) wave_max[wave] = amax;
    __syncthreads();
    float m = fmaxf(fmaxf(wave_max[0], wave_max[1]),
                    fmaxf(wave_max[2], wave_max[3]));

    const float qs = (m > 0.0f) ? (m * (1.0f / 127.0f)) : 1.0f;
    if (t == 0) scale_out[row] = qs;

    float* qrow = q_out + (size_t)row * (size_t)d;
    #pragma unroll 2
    for (int k = 0; k < iters; ++k) {
        const int j = (t + k * THREADS) * 4;
        float4 a = act[k];
        float4 q;
        // IEEE division + rintf (round-half-even) to match jnp.round(act/scale)
        q.x = fminf(127.0f, fmaxf(-127.0f, rintf(a.x / qs)));
        q.y = fminf(127.0f, fmaxf(-127.0f, rintf(a.y / qs)));
        q.z = fminf(127.0f, fmaxf(-127.0f, rintf(a.z / qs)));
        q.w = fminf(127.0f, fmaxf(-127.0f, rintf(a.w / qs)));
        *(float4*)(qrow + j) = q;
    }
}

extern "C" void kernel_launch(void* const* d_in, const int* in_sizes, int n_in,
                              void* d_out, int out_size, void* d_ws, size_t ws_size,
                              hipStream_t stream) {
    const float* input        = (const float*)d_in[0];
    const float* smooth_scale = (const float*)d_in[1];
    const int*   sorted_ids   = (const int*)d_in[2];
    const int*   topk_idx     = (const int*)d_in[3];

    const int N   = in_sizes[2];            // 16384
    const int FC1 = in_sizes[0] / N;        // 4096
    const int d   = FC1 / 2;                // 2048

    float* q_out     = (float*)d_out;
    float* scale_out = (float*)d_out + (size_t)N * (size_t)d;

    swiglu_moe_quant_kernel<<<N, THREADS, 0, stream>>>(
        input, smooth_scale, sorted_ids, topk_idx, q_out, scale_out, d);
}

// Round 2
// 386.639 us; speedup vs baseline: 1.0542x; 1.0542x over previous
//
#include <hip/hip_runtime.h>
#include <math.h>

// One block per output row. 256 threads x 8 elems = 2048 = FC1/2.
// d_out layout (all float32): [N*d] quantized values, then [N] quant_scale.
//
// R1 lesson: runtime loop bound + act[k] dynamic indexing => scratch spill
// (~1 GB extra traffic, 407 us). Template on D so act[] is fully register-
// resident with constant indices.

#define THREADS 256

__device__ __forceinline__ float fast_silu(float x) {
    // x * sigmoid(x) = x / (1 + e^-x); v_exp + v_rcp, ~1ulp each.
    float e = __expf(-x);
    return x * __builtin_amdgcn_rcpf(1.0f + e);
}

template <int D>
__global__ __launch_bounds__(THREADS) void swiglu_moe_quant_kernel(
    const float* __restrict__ input,            // [N, 2*D]
    const float* __restrict__ smooth_scale,     // [E, D]
    const int*   __restrict__ sorted_token_ids, // [N]
    const int*   __restrict__ topk_indices,     // [N]
    float* __restrict__ q_out,                  // [N, D] quantized values (f32)
    float* __restrict__ scale_out)              // [N]
{
    constexpr int ITERS = D / (THREADS * 4);    // 2 for D=2048

    const int row  = blockIdx.x;
    const int tok  = sorted_token_ids[row];
    const int exp_ = topk_indices[row];

    const float* g  = input + (size_t)tok * (size_t)(2 * D);
    const float* up = g + D;
    const float* ss = smooth_scale + (size_t)exp_ * (size_t)D;

    const int t = threadIdx.x;

    float4 act[ITERS];          // compile-time extent, constant indices -> VGPRs
    float amax = 0.0f;

    #pragma unroll
    for (int k = 0; k < ITERS; ++k) {
        const int j = (t + k * THREADS) * 4;
        float4 gv = *(const float4*)(g  + j);
        float4 uv = *(const float4*)(up + j);
        float4 sv = *(const float4*)(ss + j);
        float4 a;
        a.x = fast_silu(gv.x) * uv.x * sv.x;
        a.y = fast_silu(gv.y) * uv.y * sv.y;
        a.z = fast_silu(gv.z) * uv.z * sv.z;
        a.w = fast_silu(gv.w) * uv.w * sv.w;
        act[k] = a;
        amax = fmaxf(amax, fmaxf(fmaxf(fabsf(a.x), fabsf(a.y)),
                                 fmaxf(fabsf(a.z), fabsf(a.w))));
    }

    // 64-lane wave max reduction, then cross-wave via LDS.
    #pragma unroll
    for (int off = 32; off > 0; off >>= 1)
        amax = fmaxf(amax, __shfl_down(amax, off));

    __shared__ float wave_max[THREADS / 64];
    const int wave = t >> 6;
    const int lane = t & 63;
    if (lane == 0) wave_max[wave] = amax;
    __syncthreads();
    float m = fmaxf(fmaxf(wave_max[0], wave_max[1]),
                    fmaxf(wave_max[2], wave_max[3]));

    const float qs    = (m > 0.0f) ? (m / 127.0f) : 1.0f;  // IEEE, matches ref
    const float invqs = 1.0f / qs;                         // once per thread
    if (t == 0) scale_out[row] = qs;

    float* qrow = q_out + (size_t)row * (size_t)D;
    #pragma unroll
    for (int k = 0; k < ITERS; ++k) {
        const int j = (t + k * THREADS) * 4;
        float4 a = act[k];
        float4 q;
        q.x = fminf(127.0f, fmaxf(-127.0f, rintf(a.x * invqs)));
        q.y = fminf(127.0f, fmaxf(-127.0f, rintf(a.y * invqs)));
        q.z = fminf(127.0f, fmaxf(-127.0f, rintf(a.z * invqs)));
        q.w = fminf(127.0f, fmaxf(-127.0f, rintf(a.w * invqs)));
        *(float4*)(qrow + j) = q;
    }
}

// Generic fallback (recompute in pass 2; rows re-read hit L2). Only used if
// d != 2048 — the bench shape is always 2048.
__global__ __launch_bounds__(THREADS) void swiglu_moe_quant_generic(
    const float* __restrict__ input,
    const float* __restrict__ smooth_scale,
    const int*   __restrict__ sorted_token_ids,
    const int*   __restrict__ topk_indices,
    float* __restrict__ q_out,
    float* __restrict__ scale_out,
    int d)
{
    const int row  = blockIdx.x;
    const int tok  = sorted_token_ids[row];
    const int exp_ = topk_indices[row];
    const float* g  = input + (size_t)tok * (size_t)(2 * d);
    const float* up = g + d;
    const float* ss = smooth_scale + (size_t)exp_ * (size_t)d;
    const int t = threadIdx.x;

    float amax = 0.0f;
    for (int j = t; j < d; j += THREADS) {
        float a = fast_silu(g[j]) * up[j] * ss[j];
        amax = fmaxf(amax, fabsf(a));
    }
    #pragma unroll
    for (int off = 32; off > 0; off >>= 1)
        amax = fmaxf(amax, __shfl_down(amax, off));
    __shared__ float wave_max[THREADS / 64];
    if ((t & 63) == 0) wave_max[t >> 6] = amax;
    __syncthreads();
    float m = fmaxf(fmaxf(wave_max[0], wave_max[1]),
                    fmaxf(wave_max[2], wave_max[3]));
    const float qs    = (m > 0.0f) ? (m / 127.0f) : 1.0f;
    const float invqs = 1.0f / qs;
    if (t == 0) scale_out[row] = qs;
    float* qrow = q_out + (size_t)row * (size_t)d;
    for (int j = t; j < d; j += THREADS) {
        float a = fast_silu(g[j]) * up[j] * ss[j];
        qrow[j] = fminf(127.0f, fmaxf(-127.0f, rintf(a * invqs)));
    }
}

extern "C" void kernel_launch(void* const* d_in, const int* in_sizes, int n_in,
                              void* d_out, int out_size, void* d_ws, size_t ws_size,
                              hipStream_t stream) {
    const float* input        = (const float*)d_in[0];
    const float* smooth_scale = (const float*)d_in[1];
    const int*   sorted_ids   = (const int*)d_in[2];
    const int*   topk_idx     = (const int*)d_in[3];

    const int N   = in_sizes[2];            // 16384
    const int FC1 = in_sizes[0] / N;        // 4096
    const int d   = FC1 / 2;                // 2048

    float* q_out     = (float*)d_out;
    float* scale_out = (float*)d_out + (size_t)N * (size_t)d;

    if (d == 2048) {
        swiglu_moe_quant_kernel<2048><<<N, THREADS, 0, stream>>>(
            input, smooth_scale, sorted_ids, topk_idx, q_out, scale_out);
    } else {
        swiglu_moe_quant_generic<<<N, THREADS, 0, stream>>>(
            input, smooth_scale, sorted_ids, topk_idx, q_out, scale_out, d);
    }
}